// Round 12
// baseline (70082.739 us; speedup 1.0000x reference)
//
#include <hip/hip_runtime.h>
#include <cmath>

constexpr int kB = 64, kS = 512, kD = 128, kH = 512, kOut = 24;
constexpr int kBlocks = 256, kThreads = 512;   // grid<=256: proven coop-launchable
constexpr size_t kBarOffBytes = (size_t)5 * kB * kH * 4;   // after H0,H1,tmp1

struct Params {
  const float* x;
  const float* w0[4]; const float* b0[4];   // f,i,o,g  [512,640] / [512]
  const float* w1[4]; const float* b1[4];   // f,i,o,g  [512,1024] / [512]
  const float* fc1w; const float* fc1b;
  const float* fc2w; const float* fc2b;
  float* H0;    // 2 buffers [64][512]
  float* H1;    // 2 buffers [64][512]
  float* tmp1;  // [64][512]
  unsigned* bar; // word layout: dom slots [0,4096), dom gen @4096+d*16,
                 //              full slots [4224,8320), full gen @8320
  float* out;   // [64][24]
};

__device__ __forceinline__ float sigmoidf_(float v) {
  return 1.0f / (1.0f + expf(-v));
}

// Store-based group barrier (parallel slot stores, no RMW serialization;
// round-4 verified). Leader polls n slots with n lanes + __syncthreads_and.
__device__ __forceinline__ void sync_group(unsigned* slots, unsigned* gen,
                                           int myIdx, int n, bool leader,
                                           unsigned r) {
  const int tid = threadIdx.x;
  __syncthreads();
  if (leader) {
    if (tid == 0) {
      __threadfence();
      __hip_atomic_store(slots + myIdx * 16, r + 1, __ATOMIC_RELAXED,
                         __HIP_MEMORY_SCOPE_AGENT);
    }
    unsigned* ps = slots + (tid < n ? tid : 0) * 16;
    for (;;) {
      unsigned v = __hip_atomic_load(ps, __ATOMIC_RELAXED,
                                     __HIP_MEMORY_SCOPE_AGENT);
      if (__syncthreads_and((tid < n) ? (int)(v > r) : 1)) break;
      __builtin_amdgcn_s_sleep(1);
    }
    __threadfence();
    if (tid == 0)
      __hip_atomic_store(gen, r + 1, __ATOMIC_RELAXED,
                         __HIP_MEMORY_SCOPE_AGENT);
    __syncthreads();
  } else {
    if (tid == 0) {
      __threadfence();
      __hip_atomic_store(slots + myIdx * 16, r + 1, __ATOMIC_RELAXED,
                         __HIP_MEMORY_SCOPE_AGENT);
      while (__hip_atomic_load(gen, __ATOMIC_RELAXED,
                               __HIP_MEMORY_SCOPE_AGENT) <= r)
        __builtin_amdgcn_s_sleep(1);
      __threadfence();
    }
    __syncthreads();
  }
}

// ROUND-12: round-11 (passed, 12.8ms clean) with the STEP MERGED into one
// 13-chunk stream. Evidence: ~10us/step unaccounted after VALU+DS+barrier ->
// exposed u-load latency; the 2-deep prefetch (~400cy) < cross-XCD L3
// (~600-900cy) and the window RESETS at each phase boundary. Both phaseB(t)
// and phaseA(t+1) read only buffers written BEFORE the step's opening
// barrier (H0buf[t&1] by phaseA(t), H1buf[(t+1)&1] by phaseB(t-1)) -> all 13
// chunks are loadable immediately after the barrier.
//   chunks 0..7  -> layer1 (accB, wlds1), u from h0cur / h1prev
//   chunks 8..12 -> layer0 (accA, wlds0), u from x(t+1) / h0prev(=h0cur)
//   3-buffer register prefetch ring (static names u0/u1/u2; all indices
//   compile-time -> no scratch) spanning the whole stream: continuous
//   ~2-chunk (~500-700cy) load window. Butterflies+activations at step end.
// Lane map unchanged from round 11: l = kt*4+ci; thread owns col j0+ci, all
// 4 gates, 4 wave batches, k-slice [4kt,4kt+4) u [64+4kt,+4).
// VGPR ~190 (u ring 96 + acc 32) is free: LDS 107KB already pins 1 block/CU.
__global__ void __launch_bounds__(kThreads, 2)
lstm_persistent(Params p) {
  __shared__ float wlds0[16 * 644];    // 41.2 KB  w0 slice (row stride 644)
  __shared__ float wlds1[16 * 1028];   // 65.8 KB  w1 slice (row stride 1028)
  __shared__ float blds[32];           // biases [layer][16 rows]

  const int tid = threadIdx.x;
  const int bid = blockIdx.x;
  const int cgi = bid >> 1;
  const int bh  = bid & 1;
  const int j0  = cgi * 4;
  const int bbase = bh * 32;

  const int wv = tid >> 6;
  const int l  = tid & 63;
  const int kt = l >> 2;               // k-slice: [4kt,4kt+4) u [64+4kt,+4)
  const int ci = l & 3;                // column j0+ci
  const int bw0 = bbase + wv * 4;      // wave's first batch

  // one-time: W slices -> LDS (row r = gate*4 + col, padded strides)
  for (int idx = tid; idx < 16 * 160; idx += kThreads) {   // w0: 16 x 160 f4
    const int row = idx / 160;
    const int k4  = idx - row * 160;
    *(float4*)(wlds0 + row * 644 + k4 * 4) =
        *(const float4*)(p.w0[row >> 2] + (j0 + (row & 3)) * 640 + k4 * 4);
  }
  for (int idx = tid; idx < 16 * 256; idx += kThreads) {   // w1: 16 x 256 f4
    const int row = idx >> 8;
    const int k4  = idx & 255;
    *(float4*)(wlds1 + row * 1028 + k4 * 4) =
        *(const float4*)(p.w1[row >> 2] + (j0 + (row & 3)) * 1024 + k4 * 4);
  }
  if (tid < 16)       blds[tid] = p.b0[tid >> 2][j0 + (tid & 3)];
  else if (tid < 32)  blds[tid] = p.b1[(tid - 16) >> 2][j0 + (tid & 3)];

  // zero-init buffers read at t=0 (buffer index 1)
  if (tid < 128) {
    const int jl = tid >> 5, bb = tid & 31;
    const int b = bbase + bb;
    p.H0[kB * kH + b * kH + j0 + jl] = 0.f;
    p.H1[kB * kH + b * kH + j0 + jl] = 0.f;
  }

  float* H0buf[2] = { p.H0, p.H0 + kB * kH };
  float* H1buf[2] = { p.H1, p.H1 + kB * kH };
  float c0[4] = {0.f, 0.f, 0.f, 0.f};   // layer0 cell, per wave-batch (col ci)
  float c1[4] = {0.f, 0.f, 0.f, 0.f};   // layer1 cell

  unsigned* domSlots = p.bar + bh * 2048;
  unsigned* domGen   = p.bar + 4096 + bh * 16;
  const bool leader  = (cgi == 0);
  unsigned rnd = 0;

  sync_group(domSlots, domGen, cgi, 128, leader, rnd); rnd++;  // W/zeros ready

  // Merged step: nB layer1-chunks then nA layer0-chunks, one prefetch stream.
  auto stepMerged = [&](int nB, int nA, const float* __restrict__ h0cur,
                        const float* __restrict__ h1prev, int tn,
                        const float* __restrict__ h0prevA,
                        float* __restrict__ h1out,
                        float* __restrict__ h0outA) {
    const int C = nB + nA;
    float accB[4][4], accA[4][4];
    #pragma unroll
    for (int g = 0; g < 4; ++g)
      #pragma unroll
      for (int bb = 0; bb < 4; ++bb) { accB[g][bb] = 0.f; accA[g][bb] = 0.f; }

    auto srcAddr = [&](int c, int b, int q4) -> const float* {
      if (c < nB)
        return (c < 4) ? h0cur + b * kH + c * 128 + q4 * 4
                       : h1prev + b * kH + (c - 4) * 128 + q4 * 4;
      const int ca = c - nB;
      return (ca == 0) ? p.x + (b * kS + tn) * kD + q4 * 4
                       : h0prevA + b * kH + (ca - 1) * 128 + q4 * 4;
    };
    auto loadChunk = [&](int c, float4* dst) {
      #pragma unroll
      for (int q = 0; q < 8; ++q)
        dst[q] = *(const float4*)srcAddr(c, bw0 + (q >> 1), (q & 1) * 16 + kt);
    };
    auto computeChunk = [&](float (*acc)[4], const float* __restrict__ wl,
                            int wstride, int cl, const float4* u8) {
      #pragma unroll
      for (int half = 0; half < 2; ++half) {
        float4 wq[4];
        #pragma unroll
        for (int g = 0; g < 4; ++g)
          wq[g] = *(const float4*)(wl + (g * 4 + ci) * wstride + cl * 128 +
                                   half * 64 + kt * 4);
        #pragma unroll
        for (int g = 0; g < 4; ++g)
          #pragma unroll
          for (int bb = 0; bb < 4; ++bb) {
            const float4 u4 = u8[bb * 2 + half];
            float a = acc[g][bb];
            a = fmaf(wq[g].x, u4.x, a); a = fmaf(wq[g].y, u4.y, a);
            a = fmaf(wq[g].z, u4.z, a); a = fmaf(wq[g].w, u4.w, a);
            acc[g][bb] = a;
          }
      }
    };
    auto doChunk = [&](int c, const float4* u8) {
      if (c < nB) computeChunk(accB, wlds1, 1028, c, u8);
      else        computeChunk(accA, wlds0, 644, c - nB, u8);
    };

    // 3-deep register ring, static buffer names (no runtime ring index)
    float4 u0[8], u1[8], u2[8];
    loadChunk(0, u0);
    if (C > 1) loadChunk(1, u1);
    if (C > 2) loadChunk(2, u2);
    for (int base = 0; base < C; base += 3) {
      { doChunk(base, u0);
        if (base + 3 < C) loadChunk(base + 3, u0); }
      if (base + 1 < C) {
        doChunk(base + 1, u1);
        if (base + 4 < C) loadChunk(base + 4, u1);
      }
      if (base + 2 < C) {
        doChunk(base + 2, u2);
        if (base + 5 < C) loadChunk(base + 5, u2);
      }
    }

    // ---- layer1 reduce + activation ----
    if (nB > 0) {
      #pragma unroll
      for (int g = 0; g < 4; ++g)
        #pragma unroll
        for (int bb = 0; bb < 4; ++bb) {
          float v = accB[g][bb];
          v += __shfl_xor(v, 4, 64);
          v += __shfl_xor(v, 8, 64);
          v += __shfl_xor(v, 16, 64);
          v += __shfl_xor(v, 32, 64);
          accB[g][bb] = v;
        }
      #pragma unroll
      for (int bb = 0; bb < 4; ++bb) {
        const float fg = sigmoidf_(accB[0][bb] + blds[16 + 0 * 4 + ci]);
        const float ig = sigmoidf_(accB[1][bb] + blds[16 + 1 * 4 + ci]);
        const float og = sigmoidf_(accB[2][bb] + blds[16 + 2 * 4 + ci]);
        const float gg = tanhf(accB[3][bb] + blds[16 + 3 * 4 + ci]);
        c1[bb] = fg * c1[bb] + ig * gg;
        const float hv = og * tanhf(c1[bb]);
        if (l < 4) h1out[(bw0 + bb) * kH + j0 + ci] = hv;
      }
    }
    // ---- layer0 reduce + activation ----
    if (nA > 0) {
      #pragma unroll
      for (int g = 0; g < 4; ++g)
        #pragma unroll
        for (int bb = 0; bb < 4; ++bb) {
          float v = accA[g][bb];
          v += __shfl_xor(v, 4, 64);
          v += __shfl_xor(v, 8, 64);
          v += __shfl_xor(v, 16, 64);
          v += __shfl_xor(v, 32, 64);
          accA[g][bb] = v;
        }
      #pragma unroll
      for (int bb = 0; bb < 4; ++bb) {
        const float fg = sigmoidf_(accA[0][bb] + blds[0 * 4 + ci]);
        const float ig = sigmoidf_(accA[1][bb] + blds[1 * 4 + ci]);
        const float og = sigmoidf_(accA[2][bb] + blds[2 * 4 + ci]);
        const float gg = tanhf(accA[3][bb] + blds[3 * 4 + ci]);
        c0[bb] = fg * c0[bb] + ig * gg;
        const float hv = og * tanhf(c0[bb]);
        if (l < 4) h0outA[(bw0 + bb) * kH + j0 + ci] = hv;
      }
    }
  };

  // ---------- fused sequence: 1 domain barrier per step ----------
  // prologue: layer0 at t=0 only
  stepMerged(0, 5, nullptr, nullptr, 0, H0buf[1], nullptr, H0buf[0]);
  sync_group(domSlots, domGen, cgi, 128, leader, rnd); rnd++;

  for (int t = 0; t < kS; ++t) {
    const int nA = (t < kS - 1) ? 5 : 0;
    stepMerged(8, nA, H0buf[t & 1], H1buf[(t + 1) & 1], t + 1, H0buf[t & 1],
               H1buf[t & 1], H0buf[(t + 1) & 1]);
    sync_group(domSlots, domGen, cgi, 128, leader, rnd); rnd++;
  }

  // ---------- head: fc1 -> (FULL barrier) -> fc2 -> relu ----------
  const float* h1f = H1buf[(kS - 1) & 1];
  if (tid < 128) {
    const int jl = tid >> 5, bb = tid & 31;
    const int b = bbase + bb;
    const float* __restrict__ wrr = p.fc1w + (j0 + jl) * kH;
    const float* __restrict__ hr = h1f + b * kH;
    float s = p.fc1b[j0 + jl];
    for (int k = 0; k < kH; k += 4) {
      const float4 wv4 = *(const float4*)(wrr + k);
      const float4 hv = *(const float4*)(hr + k);
      s = fmaf(wv4.x, hv.x, s); s = fmaf(wv4.y, hv.y, s);
      s = fmaf(wv4.z, hv.z, s); s = fmaf(wv4.w, hv.w, s);
    }
    p.tmp1[b * kH + j0 + jl] = s;
  }
  // fc2 reads tmp1 across BOTH domains -> one full-grid barrier
  sync_group(p.bar + 4224, p.bar + 8320, bid, 256, bid == 0, 0u);

  if (bid < kOut && tid < kB) {
    const int b = tid;
    const float* __restrict__ wrr = p.fc2w + bid * kH;
    const float* __restrict__ tr = p.tmp1 + b * kH;
    float s = p.fc2b[bid];
    for (int k = 0; k < kH; k += 4) {
      const float4 wv4 = *(const float4*)(wrr + k);
      const float4 tv = *(const float4*)(tr + k);
      s = fmaf(wv4.x, tv.x, s); s = fmaf(wv4.y, tv.y, s);
      s = fmaf(wv4.z, tv.z, s); s = fmaf(wv4.w, tv.w, s);
    }
    p.out[b * kOut + bid] = fmaxf(s, 0.f);
  }
}

extern "C" void kernel_launch(void* const* d_in, const int* in_sizes, int n_in,
                              void* d_out, int out_size, void* d_ws, size_t ws_size,
                              hipStream_t stream) {
  (void)in_sizes; (void)n_in; (void)out_size; (void)ws_size;
  Params p;
  p.x = (const float*)d_in[0];
  p.w0[0] = (const float*)d_in[1];  p.b0[0] = (const float*)d_in[2];
  p.w0[1] = (const float*)d_in[3];  p.b0[1] = (const float*)d_in[4];
  p.w0[2] = (const float*)d_in[5];  p.b0[2] = (const float*)d_in[6];
  p.w0[3] = (const float*)d_in[7];  p.b0[3] = (const float*)d_in[8];
  p.w1[0] = (const float*)d_in[9];  p.b1[0] = (const float*)d_in[10];
  p.w1[1] = (const float*)d_in[11]; p.b1[1] = (const float*)d_in[12];
  p.w1[2] = (const float*)d_in[13]; p.b1[2] = (const float*)d_in[14];
  p.w1[3] = (const float*)d_in[15]; p.b1[3] = (const float*)d_in[16];
  p.fc1w = (const float*)d_in[17];  p.fc1b = (const float*)d_in[18];
  p.fc2w = (const float*)d_in[19];  p.fc2b = (const float*)d_in[20];

  float* ws = (float*)d_ws;
  p.H0   = ws;                       // 2 * 64*512
  p.H1   = ws + 2 * kB * kH;         // 2 * 64*512
  p.tmp1 = ws + 4 * kB * kH;         // 64*512
  p.bar  = (unsigned*)((char*)d_ws + kBarOffBytes);
  p.out  = (float*)d_out;

  // barrier state must start at 0 (ws is poisoned 0xAA before every launch)
  hipMemsetAsync((char*)d_ws + kBarOffBytes, 0, 36864, stream);

  void* args[] = { &p };
  hipLaunchCooperativeKernel(reinterpret_cast<const void*>(&lstm_persistent),
                             dim3(kBlocks), dim3(kThreads), args, 0, stream);
}

// Round 13
// 68752.448 us; speedup vs baseline: 1.0193x; 1.0193x over previous
//
#include <hip/hip_runtime.h>
#include <cmath>

constexpr int kB = 64, kS = 512, kD = 128, kH = 512, kOut = 24;
constexpr int kBlocks = 256, kThreads = 512;   // grid<=256: proven coop-launchable
constexpr size_t kBarOffBytes = (size_t)5 * kB * kH * 4;   // after H0,H1,tmp1

struct Params {
  const float* x;
  const float* w0[4]; const float* b0[4];   // f,i,o,g  [512,640] / [512]
  const float* w1[4]; const float* b1[4];   // f,i,o,g  [512,1024] / [512]
  const float* fc1w; const float* fc1b;
  const float* fc2w; const float* fc2b;
  float* H0;    // 2 buffers [64][512]
  float* H1;    // 2 buffers [64][512]
  float* tmp1;  // [64][512]
  unsigned* bar; // word layout: dom slots [0,4096), dom gen @4096+d*16,
                 //              full slots [4224,8320), full gen @8320
  float* out;   // [64][24]
};

__device__ __forceinline__ float sigmoidf_(float v) {
  return 1.0f / (1.0f + expf(-v));
}

// Store-based group barrier (parallel slot stores, no RMW serialization;
// round-4 verified). Leader polls n slots with n lanes + __syncthreads_and.
__device__ __forceinline__ void sync_group(unsigned* slots, unsigned* gen,
                                           int myIdx, int n, bool leader,
                                           unsigned r) {
  const int tid = threadIdx.x;
  __syncthreads();
  if (leader) {
    if (tid == 0) {
      __threadfence();
      __hip_atomic_store(slots + myIdx * 16, r + 1, __ATOMIC_RELAXED,
                         __HIP_MEMORY_SCOPE_AGENT);
    }
    unsigned* ps = slots + (tid < n ? tid : 0) * 16;
    for (;;) {
      unsigned v = __hip_atomic_load(ps, __ATOMIC_RELAXED,
                                     __HIP_MEMORY_SCOPE_AGENT);
      if (__syncthreads_and((tid < n) ? (int)(v > r) : 1)) break;
      __builtin_amdgcn_s_sleep(1);
    }
    __threadfence();
    if (tid == 0)
      __hip_atomic_store(gen, r + 1, __ATOMIC_RELAXED,
                         __HIP_MEMORY_SCOPE_AGENT);
    __syncthreads();
  } else {
    if (tid == 0) {
      __threadfence();
      __hip_atomic_store(slots + myIdx * 16, r + 1, __ATOMIC_RELAXED,
                         __HIP_MEMORY_SCOPE_AGENT);
      while (__hip_atomic_load(gen, __ATOMIC_RELAXED,
                               __HIP_MEMORY_SCOPE_AGENT) <= r)
        __builtin_amdgcn_s_sleep(1);
      __threadfence();
    }
    __syncthreads();
  }
}

// ROUND-13: round-12 structure with the REGISTER BUDGET FIXED.
// Round-12 failure signature: WRITE_SIZE 2.7e5 -> 1.22e8 KB, 194 GB/dispatch,
// VALUBusy 6.3%, VGPR_Count == 128 == the cap imposed by launch_bounds(512,2)
// (2 blk/CU x 8 waves = 4 waves/SIMD -> 512/4 = 128 VGPR). The 3-deep u ring
// (~190 VGPR) spilled to scratch; every prefetch round-tripped through HBM.
// LDS is 107KB -> only 1 block/CU fits ANYWAY, so (512,2) bought nothing.
// Fix: __launch_bounds__(512,1) -> 256-VGPR budget; ring fits in registers.
// (Same bug class as round 1's launch_bounds(,4) FETCH explosion.)
// Structure (unchanged from round 12): merged 13-chunk step stream --
//   chunks 0..7 layer1 (accB, wlds1), chunks 8..12 layer0(t+1) (accA, wlds0),
//   3-deep static-name register prefetch ring spanning the whole stream so
//   the u-load window (~2 chunks, 500-700cy) covers cross-XCD L3 latency
//   continuously; butterflies+activations at step end; 1 barrier/step.
__global__ void __launch_bounds__(kThreads, 1)
lstm_persistent(Params p) {
  __shared__ float wlds0[16 * 644];    // 41.2 KB  w0 slice (row stride 644)
  __shared__ float wlds1[16 * 1028];   // 65.8 KB  w1 slice (row stride 1028)
  __shared__ float blds[32];           // biases [layer][16 rows]

  const int tid = threadIdx.x;
  const int bid = blockIdx.x;
  const int cgi = bid >> 1;
  const int bh  = bid & 1;
  const int j0  = cgi * 4;
  const int bbase = bh * 32;

  const int wv = tid >> 6;
  const int l  = tid & 63;
  const int kt = l >> 2;               // k-slice: [4kt,4kt+4) u [64+4kt,+4)
  const int ci = l & 3;                // column j0+ci
  const int bw0 = bbase + wv * 4;      // wave's first batch

  // one-time: W slices -> LDS (row r = gate*4 + col, padded strides)
  for (int idx = tid; idx < 16 * 160; idx += kThreads) {   // w0: 16 x 160 f4
    const int row = idx / 160;
    const int k4  = idx - row * 160;
    *(float4*)(wlds0 + row * 644 + k4 * 4) =
        *(const float4*)(p.w0[row >> 2] + (j0 + (row & 3)) * 640 + k4 * 4);
  }
  for (int idx = tid; idx < 16 * 256; idx += kThreads) {   // w1: 16 x 256 f4
    const int row = idx >> 8;
    const int k4  = idx & 255;
    *(float4*)(wlds1 + row * 1028 + k4 * 4) =
        *(const float4*)(p.w1[row >> 2] + (j0 + (row & 3)) * 1024 + k4 * 4);
  }
  if (tid < 16)       blds[tid] = p.b0[tid >> 2][j0 + (tid & 3)];
  else if (tid < 32)  blds[tid] = p.b1[(tid - 16) >> 2][j0 + (tid & 3)];

  // zero-init buffers read at t=0 (buffer index 1)
  if (tid < 128) {
    const int jl = tid >> 5, bb = tid & 31;
    const int b = bbase + bb;
    p.H0[kB * kH + b * kH + j0 + jl] = 0.f;
    p.H1[kB * kH + b * kH + j0 + jl] = 0.f;
  }

  float* H0buf[2] = { p.H0, p.H0 + kB * kH };
  float* H1buf[2] = { p.H1, p.H1 + kB * kH };
  float c0[4] = {0.f, 0.f, 0.f, 0.f};   // layer0 cell, per wave-batch (col ci)
  float c1[4] = {0.f, 0.f, 0.f, 0.f};   // layer1 cell

  unsigned* domSlots = p.bar + bh * 2048;
  unsigned* domGen   = p.bar + 4096 + bh * 16;
  const bool leader  = (cgi == 0);
  unsigned rnd = 0;

  sync_group(domSlots, domGen, cgi, 128, leader, rnd); rnd++;  // W/zeros ready

  // Merged step: nB layer1-chunks then nA layer0-chunks, one prefetch stream.
  auto stepMerged = [&](int nB, int nA, const float* __restrict__ h0cur,
                        const float* __restrict__ h1prev, int tn,
                        const float* __restrict__ h0prevA,
                        float* __restrict__ h1out,
                        float* __restrict__ h0outA) {
    const int C = nB + nA;
    float accB[4][4], accA[4][4];
    #pragma unroll
    for (int g = 0; g < 4; ++g)
      #pragma unroll
      for (int bb = 0; bb < 4; ++bb) { accB[g][bb] = 0.f; accA[g][bb] = 0.f; }

    auto srcAddr = [&](int c, int b, int q4) -> const float* {
      if (c < nB)
        return (c < 4) ? h0cur + b * kH + c * 128 + q4 * 4
                       : h1prev + b * kH + (c - 4) * 128 + q4 * 4;
      const int ca = c - nB;
      return (ca == 0) ? p.x + (b * kS + tn) * kD + q4 * 4
                       : h0prevA + b * kH + (ca - 1) * 128 + q4 * 4;
    };
    auto loadChunk = [&](int c, float4* dst) {
      #pragma unroll
      for (int q = 0; q < 8; ++q)
        dst[q] = *(const float4*)srcAddr(c, bw0 + (q >> 1), (q & 1) * 16 + kt);
    };
    auto computeChunk = [&](float (*acc)[4], const float* __restrict__ wl,
                            int wstride, int cl, const float4* u8) {
      #pragma unroll
      for (int half = 0; half < 2; ++half) {
        float4 wq[4];
        #pragma unroll
        for (int g = 0; g < 4; ++g)
          wq[g] = *(const float4*)(wl + (g * 4 + ci) * wstride + cl * 128 +
                                   half * 64 + kt * 4);
        #pragma unroll
        for (int g = 0; g < 4; ++g)
          #pragma unroll
          for (int bb = 0; bb < 4; ++bb) {
            const float4 u4 = u8[bb * 2 + half];
            float a = acc[g][bb];
            a = fmaf(wq[g].x, u4.x, a); a = fmaf(wq[g].y, u4.y, a);
            a = fmaf(wq[g].z, u4.z, a); a = fmaf(wq[g].w, u4.w, a);
            acc[g][bb] = a;
          }
      }
    };
    auto doChunk = [&](int c, const float4* u8) {
      if (c < nB) computeChunk(accB, wlds1, 1028, c, u8);
      else        computeChunk(accA, wlds0, 644, c - nB, u8);
    };

    // 3-deep register ring, static buffer names (no runtime ring index)
    float4 u0[8], u1[8], u2[8];
    loadChunk(0, u0);
    if (C > 1) loadChunk(1, u1);
    if (C > 2) loadChunk(2, u2);
    for (int base = 0; base < C; base += 3) {
      { doChunk(base, u0);
        if (base + 3 < C) loadChunk(base + 3, u0); }
      if (base + 1 < C) {
        doChunk(base + 1, u1);
        if (base + 4 < C) loadChunk(base + 4, u1);
      }
      if (base + 2 < C) {
        doChunk(base + 2, u2);
        if (base + 5 < C) loadChunk(base + 5, u2);
      }
    }

    // ---- layer1 reduce + activation ----
    if (nB > 0) {
      #pragma unroll
      for (int g = 0; g < 4; ++g)
        #pragma unroll
        for (int bb = 0; bb < 4; ++bb) {
          float v = accB[g][bb];
          v += __shfl_xor(v, 4, 64);
          v += __shfl_xor(v, 8, 64);
          v += __shfl_xor(v, 16, 64);
          v += __shfl_xor(v, 32, 64);
          accB[g][bb] = v;
        }
      #pragma unroll
      for (int bb = 0; bb < 4; ++bb) {
        const float fg = sigmoidf_(accB[0][bb] + blds[16 + 0 * 4 + ci]);
        const float ig = sigmoidf_(accB[1][bb] + blds[16 + 1 * 4 + ci]);
        const float og = sigmoidf_(accB[2][bb] + blds[16 + 2 * 4 + ci]);
        const float gg = tanhf(accB[3][bb] + blds[16 + 3 * 4 + ci]);
        c1[bb] = fg * c1[bb] + ig * gg;
        const float hv = og * tanhf(c1[bb]);
        if (l < 4) h1out[(bw0 + bb) * kH + j0 + ci] = hv;
      }
    }
    // ---- layer0 reduce + activation ----
    if (nA > 0) {
      #pragma unroll
      for (int g = 0; g < 4; ++g)
        #pragma unroll
        for (int bb = 0; bb < 4; ++bb) {
          float v = accA[g][bb];
          v += __shfl_xor(v, 4, 64);
          v += __shfl_xor(v, 8, 64);
          v += __shfl_xor(v, 16, 64);
          v += __shfl_xor(v, 32, 64);
          accA[g][bb] = v;
        }
      #pragma unroll
      for (int bb = 0; bb < 4; ++bb) {
        const float fg = sigmoidf_(accA[0][bb] + blds[0 * 4 + ci]);
        const float ig = sigmoidf_(accA[1][bb] + blds[1 * 4 + ci]);
        const float og = sigmoidf_(accA[2][bb] + blds[2 * 4 + ci]);
        const float gg = tanhf(accA[3][bb] + blds[3 * 4 + ci]);
        c0[bb] = fg * c0[bb] + ig * gg;
        const float hv = og * tanhf(c0[bb]);
        if (l < 4) h0outA[(bw0 + bb) * kH + j0 + ci] = hv;
      }
    }
  };

  // ---------- fused sequence: 1 domain barrier per step ----------
  // prologue: layer0 at t=0 only
  stepMerged(0, 5, nullptr, nullptr, 0, H0buf[1], nullptr, H0buf[0]);
  sync_group(domSlots, domGen, cgi, 128, leader, rnd); rnd++;

  for (int t = 0; t < kS; ++t) {
    const int nA = (t < kS - 1) ? 5 : 0;
    stepMerged(8, nA, H0buf[t & 1], H1buf[(t + 1) & 1], t + 1, H0buf[t & 1],
               H1buf[t & 1], H0buf[(t + 1) & 1]);
    sync_group(domSlots, domGen, cgi, 128, leader, rnd); rnd++;
  }

  // ---------- head: fc1 -> (FULL barrier) -> fc2 -> relu ----------
  const float* h1f = H1buf[(kS - 1) & 1];
  if (tid < 128) {
    const int jl = tid >> 5, bb = tid & 31;
    const int b = bbase + bb;
    const float* __restrict__ wrr = p.fc1w + (j0 + jl) * kH;
    const float* __restrict__ hr = h1f + b * kH;
    float s = p.fc1b[j0 + jl];
    for (int k = 0; k < kH; k += 4) {
      const float4 wv4 = *(const float4*)(wrr + k);
      const float4 hv = *(const float4*)(hr + k);
      s = fmaf(wv4.x, hv.x, s); s = fmaf(wv4.y, hv.y, s);
      s = fmaf(wv4.z, hv.z, s); s = fmaf(wv4.w, hv.w, s);
    }
    p.tmp1[b * kH + j0 + jl] = s;
  }
  // fc2 reads tmp1 across BOTH domains -> one full-grid barrier
  sync_group(p.bar + 4224, p.bar + 8320, bid, 256, bid == 0, 0u);

  if (bid < kOut && tid < kB) {
    const int b = tid;
    const float* __restrict__ wrr = p.fc2w + bid * kH;
    const float* __restrict__ tr = p.tmp1 + b * kH;
    float s = p.fc2b[bid];
    for (int k = 0; k < kH; k += 4) {
      const float4 wv4 = *(const float4*)(wrr + k);
      const float4 tv = *(const float4*)(tr + k);
      s = fmaf(wv4.x, tv.x, s); s = fmaf(wv4.y, tv.y, s);
      s = fmaf(wv4.z, tv.z, s); s = fmaf(wv4.w, tv.w, s);
    }
    p.out[b * kOut + bid] = fmaxf(s, 0.f);
  }
}

extern "C" void kernel_launch(void* const* d_in, const int* in_sizes, int n_in,
                              void* d_out, int out_size, void* d_ws, size_t ws_size,
                              hipStream_t stream) {
  (void)in_sizes; (void)n_in; (void)out_size; (void)ws_size;
  Params p;
  p.x = (const float*)d_in[0];
  p.w0[0] = (const float*)d_in[1];  p.b0[0] = (const float*)d_in[2];
  p.w0[1] = (const float*)d_in[3];  p.b0[1] = (const float*)d_in[4];
  p.w0[2] = (const float*)d_in[5];  p.b0[2] = (const float*)d_in[6];
  p.w0[3] = (const float*)d_in[7];  p.b0[3] = (const float*)d_in[8];
  p.w1[0] = (const float*)d_in[9];  p.b1[0] = (const float*)d_in[10];
  p.w1[1] = (const float*)d_in[11]; p.b1[1] = (const float*)d_in[12];
  p.w1[2] = (const float*)d_in[13]; p.b1[2] = (const float*)d_in[14];
  p.w1[3] = (const float*)d_in[15]; p.b1[3] = (const float*)d_in[16];
  p.fc1w = (const float*)d_in[17];  p.fc1b = (const float*)d_in[18];
  p.fc2w = (const float*)d_in[19];  p.fc2b = (const float*)d_in[20];

  float* ws = (float*)d_ws;
  p.H0   = ws;                       // 2 * 64*512
  p.H1   = ws + 2 * kB * kH;         // 2 * 64*512
  p.tmp1 = ws + 4 * kB * kH;         // 64*512
  p.bar  = (unsigned*)((char*)d_ws + kBarOffBytes);
  p.out  = (float*)d_out;

  // barrier state must start at 0 (ws is poisoned 0xAA before every launch)
  hipMemsetAsync((char*)d_ws + kBarOffBytes, 0, 36864, stream);

  void* args[] = { &p };
  hipLaunchCooperativeKernel(reinterpret_cast<const void*>(&lstm_persistent),
                             dim3(kBlocks), dim3(kThreads), args, 0, stream);
}